// Round 3
// baseline (567.384 us; speedup 1.0000x reference)
//
#include <hip/hip_runtime.h>

// MSRSA fused attention, MI355X gfx950.
// out[B,H,N,D] fp32  ++  attn[B,H,N,N] fp32   (d_out = out | attn, flat)
// B=8 H=8 N=1024 D=64.
//
// Design:
//  - detect_kernel: classify attention_mask storage (int32 / uint8 / float) at runtime.
//  - pack_kernel:   2 bits per (b,n,m): bit0=mask, bit1=adjacency!=0  -> 2 MiB in d_ws.
//  - msrsa_main:    per block: 64 Q-rows of one (b,h). bf16x3 MFMA (hi/lo split) for
//                   QK^T and PV => ~1e-5..1e-4 abs error (fp32-like). Pass A: row sums
//                   of exp(s). Pass B: recompute s, store attn = exp(s)*inv, P->LDS,
//                   PV MFMA. s = qk * coef, coef in {0, 1/8, (1+wA[h])/8} from packed
//                   bits. exp(0)=1 for masked entries matches reference (softmax is
//                   shift-invariant; |s|<~35 so no max subtraction needed in fp32).
//  - XCD swizzle: logical = (p%8)*128 + p/8 puts the 16 blocks sharing one (b,h)
//                   K/V panel on the same XCD (8 panels * 512 KiB = 4 MiB = one L2).

typedef __attribute__((ext_vector_type(8))) short short8;
typedef __attribute__((ext_vector_type(4))) short short4v;
typedef __attribute__((ext_vector_type(4))) float float4v;

#define BDIM 8
#define HDIM 8
#define NDIM 1024
#define DDIM 64

__device__ __forceinline__ short f2bf(float x){
  unsigned int u = __float_as_uint(x);
  unsigned int r = (u + 0x7fffu + ((u >> 16) & 1u)) >> 16;
  return (short)r;
}
__device__ __forceinline__ float bf2f(short s){
  return __uint_as_float(((unsigned int)(unsigned short)s) << 16);
}
// XOR-swizzled element index inside a [64][64] bf16 tile (row stride 128 B).
__device__ __forceinline__ int swz(int r, int c){
  return r * 64 + ((((c >> 3) ^ (r & 7))) << 3) + (c & 7);
}
__device__ __forceinline__ short8 ldsFrag(const short* base, int row, int ch){
  return *(const short8*)(base + row * 64 + ((ch ^ (row & 7)) << 3));
}
__device__ __forceinline__ float4v mfma16(short8 a, short8 b, float4v c){
  return __builtin_amdgcn_mfma_f32_16x16x32_bf16(a, b, c, 0, 0, 0);
}

// Stage a [64 rows][64 cols] fp32 tile -> hi/lo bf16 LDS tiles (swizzled).
// Coalesced: per instr, 4 consecutive lanes cover 64 contiguous bytes of one row.
__device__ __forceinline__ void stageHL(const float* __restrict__ gsrc,
                                        short* ldsH, short* ldsL, int tid){
  const int r  = tid >> 2;
  const int cb = (tid & 3) << 2;          // 0,4,8,12
  #pragma unroll
  for (int k = 0; k < 4; ++k){
    const int c = cb + (k << 4);
    float4v v = *(const float4v*)(gsrc + r * 64 + c);
    short4v hv, lv;
    #pragma unroll
    for (int j = 0; j < 4; ++j){
      float x = v[j];
      short hb = f2bf(x);
      hv[j] = hb;
      lv[j] = f2bf(x - bf2f(hb));
    }
    const int idx = swz(r, c);            // 8-byte aligned (c&7 in {0,4})
    *(short4v*)(ldsH + idx) = hv;
    *(short4v*)(ldsL + idx) = lv;
  }
}

// Stage V [64 m][64 d] fp32 -> transposed VT [d][m] hi/lo bf16 LDS tiles (swizzled).
__device__ __forceinline__ void stageVT(const float* __restrict__ gsrc,
                                        short* ldsH, short* ldsL, int tid){
  const int m  = tid >> 2;
  const int db = (tid & 3) << 2;
  #pragma unroll
  for (int k = 0; k < 4; ++k){
    const int d0 = db + (k << 4);
    float4v v = *(const float4v*)(gsrc + m * 64 + d0);
    #pragma unroll
    for (int j = 0; j < 4; ++j){
      float x = v[j];
      short hb = f2bf(x);
      const int idx = swz(d0 + j, m);
      ldsH[idx] = hb;
      ldsL[idx] = f2bf(x - bf2f(hb));
    }
  }
}

__global__ void detect_kernel(const unsigned int* __restrict__ m, int* __restrict__ flag){
  __shared__ unsigned int fl;
  if (threadIdx.x == 0) fl = 0u;
  __syncthreads();
  unsigned int loc = 0u;
  #pragma unroll
  for (int j = 0; j < 4; ++j){
    unsigned int w = m[threadIdx.x * 4 + j];
    if (w == 0x3f800000u) loc |= 2u;      // float 1.0 pattern
    else if (w > 1u)      loc |= 1u;      // packed-byte pattern
  }
  atomicOr(&fl, loc);
  __syncthreads();
  if (threadIdx.x == 0){
    int code = 0;                          // int32 {0,1}
    if (fl & 2u) code = 2;                 // float
    else if (fl & 1u) code = 1;            // uint8
    flag[0] = code;
  }
}

__global__ void pack_kernel(const void* __restrict__ maskp, const float* __restrict__ adjp,
                            const int* __restrict__ flagp, unsigned int* __restrict__ pk){
  const int wi = blockIdx.x * 256 + threadIdx.x;     // 524288 words total
  const size_t e0 = (size_t)wi << 4;
  const int fl = flagp[0];
  unsigned int word = 0u;
  if (fl == 0){
    const int* mp = (const int*)maskp + e0;
    #pragma unroll
    for (int j = 0; j < 16; ++j) if (mp[j] != 0) word |= (1u << (2 * j));
  } else if (fl == 1){
    const unsigned char* mp = (const unsigned char*)maskp + e0;
    #pragma unroll
    for (int j = 0; j < 16; ++j) if (mp[j] != 0) word |= (1u << (2 * j));
  } else {
    const float* mp = (const float*)maskp + e0;
    #pragma unroll
    for (int j = 0; j < 16; ++j) if (mp[j] != 0.f) word |= (1u << (2 * j));
  }
  const float* ap = adjp + e0;
  #pragma unroll
  for (int j = 0; j < 16; ++j) if (ap[j] != 0.f) word |= (2u << (2 * j));
  pk[wi] = word;
}

template<int PACKED>
__global__ __launch_bounds__(256) void msrsa_main(
    const float* __restrict__ Q, const float* __restrict__ K, const float* __restrict__ V,
    const void* __restrict__ maskp, const float* __restrict__ adjp,
    const float* __restrict__ wAp,
    float* __restrict__ outp, float* __restrict__ attnp,
    const unsigned int* __restrict__ pk, const int* __restrict__ flagp)
{
  // XCD-aware bijective swizzle: physical p -> logical blk so that the 16
  // blocks sharing one (b,h) K/V panel land on the same XCD (p%8).
  const int p   = blockIdx.x;
  const int blk = (p & 7) * 128 + (p >> 3);
  const int b  = blk >> 7;
  const int h  = (blk >> 4) & 7;
  const int rb = blk & 15;
  const int n0 = rb << 6;
  const int tid  = threadIdx.x;
  const int wid  = tid >> 6;
  const int lane = tid & 63;
  const int g    = lane >> 4;
  const int q    = lane & 15;

  const size_t bh = (size_t)(b * HDIM + h);
  const float* Qb = Q + bh * (NDIM * DDIM) + (size_t)n0 * DDIM;
  const float* Kb = K + bh * (NDIM * DDIM);
  const float* Vb = V + bh * (NDIM * DDIM);
  const float c0 = 0.125f;
  const float cA = (1.0f + wAp[h]) * 0.125f;
  int flag = 0;
  if (!PACKED) flag = flagp[0];
  const size_t bNN = (size_t)b * ((size_t)NDIM * NDIM);

  __shared__ __align__(16) short A0h[4096], A0l[4096];   // Q staging, then P tiles
  __shared__ __align__(16) short A1h[4096], A1l[4096];   // K tiles
  __shared__ __align__(16) short A2h[4096], A2l[4096];   // V^T tiles

  stageHL(Qb, A0h, A0l, tid);
  __syncthreads();
  const int arow = (wid << 4) + q;
  short8 qh[2], ql[2];
  qh[0] = ldsFrag(A0h, arow, g);  qh[1] = ldsFrag(A0h, arow, g + 4);
  ql[0] = ldsFrag(A0l, arow, g);  ql[1] = ldsFrag(A0l, arow, g + 4);

  int nloc[4];
  #pragma unroll
  for (int i = 0; i < 4; ++i) nloc[i] = (wid << 4) + (g << 2) + i;

  // ---------------- pass A: row sums ----------------
  float psum[4] = {0.f, 0.f, 0.f, 0.f};
  for (int ms = 0; ms < 16; ++ms){
    const int m0 = ms << 6;
    __syncthreads();
    stageHL(Kb + m0 * DDIM, A1h, A1l, tid);
    __syncthreads();
    #pragma unroll
    for (int mt = 0; mt < 4; ++mt){
      float4v acc = {0.f, 0.f, 0.f, 0.f};
      const int brow = (mt << 4) + q;
      #pragma unroll
      for (int ks = 0; ks < 2; ++ks){
        short8 kh = ldsFrag(A1h, brow, g + (ks << 2));
        short8 kl = ldsFrag(A1l, brow, g + (ks << 2));
        acc = mfma16(qh[ks], kh, acc);
        acc = mfma16(qh[ks], kl, acc);
        acc = mfma16(ql[ks], kh, acc);
      }
      #pragma unroll
      for (int i = 0; i < 4; ++i){
        const int n = n0 + nloc[i];
        float coef;
        if (PACKED){
          unsigned int wv = pk[((unsigned)b << 16) + ((unsigned)n << 6) + (unsigned)((m0 >> 4) + mt)];
          unsigned int bits = (wv >> (q << 1)) & 3u;
          coef = (bits & 1u) ? ((bits & 2u) ? cA : c0) : 0.0f;
        } else {
          const size_t ei = bNN + (size_t)n * NDIM + (size_t)(m0 + (mt << 4) + q);
          bool mk;
          if (flag == 0)      mk = ((const int*)maskp)[ei] != 0;
          else if (flag == 1) mk = ((const unsigned char*)maskp)[ei] != 0;
          else                mk = ((const float*)maskp)[ei] != 0.f;
          float av = adjp[ei];
          coef = mk ? ((av != 0.f) ? cA : c0) : 0.f;
        }
        psum[i] += __expf(acc[i] * coef);
      }
    }
  }
  float inv[4];
  #pragma unroll
  for (int i = 0; i < 4; ++i){
    float s = psum[i];
    s += __shfl_xor(s, 1, 16);
    s += __shfl_xor(s, 2, 16);
    s += __shfl_xor(s, 4, 16);
    s += __shfl_xor(s, 8, 16);
    inv[i] = 1.0f / s;
  }

  // ---------------- pass B: attn store + PV ----------------
  float4v oacc[4];
  #pragma unroll
  for (int dt = 0; dt < 4; ++dt) oacc[dt] = (float4v){0.f, 0.f, 0.f, 0.f};

  float* aRow[4];
  #pragma unroll
  for (int i = 0; i < 4; ++i)
    aRow[i] = attnp + (bh * NDIM + (size_t)(n0 + nloc[i])) * (size_t)NDIM;

  for (int ms = 0; ms < 16; ++ms){
    const int m0 = ms << 6;
    __syncthreads();
    stageHL(Kb + m0 * DDIM, A1h, A1l, tid);
    stageVT(Vb + m0 * DDIM, A2h, A2l, tid);
    __syncthreads();
    #pragma unroll
    for (int mt = 0; mt < 4; ++mt){
      float4v acc = {0.f, 0.f, 0.f, 0.f};
      const int brow = (mt << 4) + q;
      #pragma unroll
      for (int ks = 0; ks < 2; ++ks){
        short8 kh = ldsFrag(A1h, brow, g + (ks << 2));
        short8 kl = ldsFrag(A1l, brow, g + (ks << 2));
        acc = mfma16(qh[ks], kh, acc);
        acc = mfma16(qh[ks], kl, acc);
        acc = mfma16(ql[ks], kh, acc);
      }
      #pragma unroll
      for (int i = 0; i < 4; ++i){
        const int n = n0 + nloc[i];
        float coef;
        if (PACKED){
          unsigned int wv = pk[((unsigned)b << 16) + ((unsigned)n << 6) + (unsigned)((m0 >> 4) + mt)];
          unsigned int bits = (wv >> (q << 1)) & 3u;
          coef = (bits & 1u) ? ((bits & 2u) ? cA : c0) : 0.0f;
        } else {
          const size_t ei = bNN + (size_t)n * NDIM + (size_t)(m0 + (mt << 4) + q);
          bool mk;
          if (flag == 0)      mk = ((const int*)maskp)[ei] != 0;
          else if (flag == 1) mk = ((const unsigned char*)maskp)[ei] != 0;
          else                mk = ((const float*)maskp)[ei] != 0.f;
          float av = adjp[ei];
          coef = mk ? ((av != 0.f) ? cA : c0) : 0.f;
        }
        float p2 = __expf(acc[i] * coef);
        float at = p2 * inv[i];
        aRow[i][m0 + (mt << 4) + q] = at;
        short ph = f2bf(at);
        const int pi = swz(nloc[i], (mt << 4) + q);
        A0h[pi] = ph;
        A0l[pi] = f2bf(at - bf2f(ph));
      }
    }
    __syncthreads();
    #pragma unroll
    for (int ks = 0; ks < 2; ++ks){
      short8 pah = ldsFrag(A0h, arow, g + (ks << 2));
      short8 pal = ldsFrag(A0l, arow, g + (ks << 2));
      #pragma unroll
      for (int dt = 0; dt < 4; ++dt){
        short8 vh = ldsFrag(A2h, (dt << 4) + q, g + (ks << 2));
        short8 vl = ldsFrag(A2l, (dt << 4) + q, g + (ks << 2));
        oacc[dt] = mfma16(pah, vh, oacc[dt]);
        oacc[dt] = mfma16(pah, vl, oacc[dt]);
        oacc[dt] = mfma16(pal, vh, oacc[dt]);
      }
    }
  }

  #pragma unroll
  for (int dt = 0; dt < 4; ++dt){
    #pragma unroll
    for (int i = 0; i < 4; ++i){
      outp[(bh * NDIM + (size_t)(n0 + nloc[i])) * DDIM + (dt << 4) + q] = oacc[dt][i];
    }
  }
}

extern "C" void kernel_launch(void* const* d_in, const int* in_sizes, int n_in,
                              void* d_out, int out_size, void* d_ws, size_t ws_size,
                              hipStream_t stream){
  const float* Q    = (const float*)d_in[0];
  const float* K    = (const float*)d_in[1];
  const float* V    = (const float*)d_in[2];
  const void*  mskp = d_in[3];
  const float* adjp = (const float*)d_in[4];
  // d_in[5] (row_subtracted_distance_matrix) unused by reference
  const float* wAp  = (const float*)d_in[6];

  float* outp  = (float*)d_out;
  float* attnp = outp + (size_t)BDIM * HDIM * NDIM * DDIM;

  int* flagp = (int*)d_ws;
  unsigned int* pkbuf = (unsigned int*)((char*)d_ws + 256);
  const bool packed = ws_size >= ((size_t)2 * 1024 * 1024 + 256);

  hipLaunchKernelGGL(detect_kernel, dim3(1), dim3(256), 0, stream,
                     (const unsigned int*)mskp, flagp);
  if (packed){
    hipLaunchKernelGGL(pack_kernel, dim3(2048), dim3(256), 0, stream,
                       mskp, adjp, flagp, pkbuf);
    hipLaunchKernelGGL(msrsa_main<1>, dim3(1024), dim3(256), 0, stream,
                       Q, K, V, mskp, adjp, wAp, outp, attnp, pkbuf, flagp);
  } else {
    hipLaunchKernelGGL(msrsa_main<0>, dim3(1024), dim3(256), 0, stream,
                       Q, K, V, mskp, adjp, wAp, outp, attnp, pkbuf, flagp);
  }
}

// Round 4
// 507.980 us; speedup vs baseline: 1.1169x; 1.1169x over previous
//
#include <hip/hip_runtime.h>

// MSRSA fused attention, MI355X gfx950.
// out[B,H,N,D] fp32  ++  attn[B,H,N,N] fp32   (d_out = out | attn, flat)
// B=8 H=8 N=1024 D=64.
//
// R3 -> R4 change (measured: main 254us, VALUBusy 40%, MfmaUtil 12%, hbm 15.6%):
//  staging conversion (fp32->bf16 hi/lo) was recomputed 32x per K tile inside the
//  hot loop => VALU-bound. Now a one-shot precvt_kernel converts Q/K/V into
//  pre-swizzled bf16 hi/lo tile planes (48 MB in d_ws); the main kernel stages
//  tiles with global_load_lds width=16 (linear dest, swizzle baked into storage;
//  ds_read side applies the same XOR -> rule 21 both-sides-consistent).
//  pack_kernel rewritten with coalesced 16B/lane loads + LDS redistribution.
//
//  Tiers (graph-safe, ws_size is constant per process):
//   MODE2: ws >= 256+2MB+48MB : packed bits + precvt tiles   (fast path)
//   MODE1: ws >= 256+2MB      : packed bits, inline convert
//   MODE0: tiny ws            : raw mask/adj reads, inline convert

typedef __attribute__((ext_vector_type(8))) short short8;
typedef __attribute__((ext_vector_type(4))) short short4v;
typedef __attribute__((ext_vector_type(4))) float float4v;
typedef __attribute__((ext_vector_type(4))) unsigned int uint4v;

#define BDIM 8
#define HDIM 8
#define NDIM 1024
#define DDIM 64

__device__ __forceinline__ short f2bf(float x){
  unsigned int u = __float_as_uint(x);
  unsigned int r = (u + 0x7fffu + ((u >> 16) & 1u)) >> 16;
  return (short)r;
}
__device__ __forceinline__ float bf2f(short s){
  return __uint_as_float(((unsigned int)(unsigned short)s) << 16);
}
// XOR-swizzled element index inside a [64][64] bf16 tile (row stride 128 B).
__device__ __forceinline__ int swz(int r, int c){
  return r * 64 + ((((c >> 3) ^ (r & 7))) << 3) + (c & 7);
}
__device__ __forceinline__ short8 ldsFrag(const short* base, int row, int ch){
  return *(const short8*)(base + row * 64 + ((ch ^ (row & 7)) << 3));
}
__device__ __forceinline__ float4v mfma16(short8 a, short8 b, float4v c){
  return __builtin_amdgcn_mfma_f32_16x16x32_bf16(a, b, c, 0, 0, 0);
}

// async global->LDS 16B/lane. LDS dest must be wave-uniform; HW adds lane*16.
__device__ __forceinline__ void gload16(const void* g, void* l){
  __builtin_amdgcn_global_load_lds(
      (const __attribute__((address_space(1))) unsigned int*)g,
      (__attribute__((address_space(3))) unsigned int*)l, 16, 0, 0);
}
// copy one 16 KiB pre-swizzled tile (hi 8K | lo 8K) into LDS, all 4 waves.
__device__ __forceinline__ void copyTile(const char* g, char* l, int wid, int lane){
  #pragma unroll
  for (int c = 0; c < 4; ++c){
    gload16(g + (c << 12) + (wid << 10) + (lane << 4),
            l + (c << 12) + (wid << 10));
  }
}

// ---- fallback inline staging (MODE<2), identical numerics to R3 ----
__device__ __forceinline__ void stageHL(const float* __restrict__ gsrc,
                                        short* ldsH, short* ldsL, int tid){
  const int r  = tid >> 2;
  const int cb = (tid & 3) << 2;
  #pragma unroll
  for (int k = 0; k < 4; ++k){
    const int c = cb + (k << 4);
    float4v v = *(const float4v*)(gsrc + r * 64 + c);
    short4v hv, lv;
    #pragma unroll
    for (int j = 0; j < 4; ++j){
      float x = v[j];
      short hb = f2bf(x);
      hv[j] = hb;
      lv[j] = f2bf(x - bf2f(hb));
    }
    const int idx = swz(r, c);
    *(short4v*)(ldsH + idx) = hv;
    *(short4v*)(ldsL + idx) = lv;
  }
}
__device__ __forceinline__ void stageVT(const float* __restrict__ gsrc,
                                        short* ldsH, short* ldsL, int tid){
  const int m  = tid >> 2;
  const int db = (tid & 3) << 2;
  #pragma unroll
  for (int k = 0; k < 4; ++k){
    const int d0 = db + (k << 4);
    float4v v = *(const float4v*)(gsrc + m * 64 + d0);
    #pragma unroll
    for (int j = 0; j < 4; ++j){
      float x = v[j];
      short hb = f2bf(x);
      const int idx = swz(d0 + j, m);
      ldsH[idx] = hb;
      ldsL[idx] = f2bf(x - bf2f(hb));
    }
  }
}

__global__ void detect_kernel(const unsigned int* __restrict__ m, int* __restrict__ flag){
  __shared__ unsigned int fl;
  if (threadIdx.x == 0) fl = 0u;
  __syncthreads();
  unsigned int loc = 0u;
  #pragma unroll
  for (int j = 0; j < 4; ++j){
    unsigned int w = m[threadIdx.x * 4 + j];
    if (w == 0x3f800000u) loc |= 2u;      // float 1.0 pattern
    else if (w > 1u)      loc |= 1u;      // packed-byte pattern
  }
  atomicOr(&fl, loc);
  __syncthreads();
  if (threadIdx.x == 0){
    int code = 0;                          // int32 {0,1}
    if (fl & 2u) code = 2;                 // float
    else if (fl & 1u) code = 1;            // uint8
    flag[0] = code;
  }
}

// 2 bits per (b,n,m): bit0=mask, bit1=adj!=0. Coalesced 16B/lane + LDS (pad 17).
__global__ __launch_bounds__(256) void pack_kernel(const void* __restrict__ maskp,
                                                   const float* __restrict__ adjp,
                                                   const int* __restrict__ flagp,
                                                   unsigned int* __restrict__ pk){
  __shared__ unsigned int st[256 * 17];
  const int t = threadIdx.x;
  const size_t ebase = (size_t)blockIdx.x * 4096;   // element base
  const int fl = flagp[0];
  unsigned int word = 0u;

  if (fl == 1){
    // uint8 mask: thread's 16 consecutive bytes = one aligned 16B load.
    uint4v mv = *(const uint4v*)((const unsigned char*)maskp + ebase + (size_t)t * 16);
    #pragma unroll
    for (int j = 0; j < 16; ++j){
      unsigned int byte = (mv[j >> 2] >> ((j & 3) * 8)) & 0xffu;
      if (byte) word |= (1u << (2 * j));
    }
  } else {
    const unsigned int* mp = (const unsigned int*)maskp + ebase;
    #pragma unroll
    for (int p = 0; p < 4; ++p){
      uint4v v = *(const uint4v*)(mp + (size_t)((p << 8) + t) * 4);
      #pragma unroll
      for (int j = 0; j < 4; ++j){
        const int E = ((p << 8) + t) * 4 + j;
        st[(E >> 4) * 17 + (E & 15)] = v[j];
      }
    }
    __syncthreads();
    if (fl == 0){
      #pragma unroll
      for (int j = 0; j < 16; ++j) if (st[t * 17 + j] != 0u) word |= (1u << (2 * j));
    } else {
      #pragma unroll
      for (int j = 0; j < 16; ++j) if ((st[t * 17 + j] << 1) != 0u) word |= (1u << (2 * j));
    }
    __syncthreads();
  }

  {
    const unsigned int* ap = (const unsigned int*)adjp + ebase;
    #pragma unroll
    for (int p = 0; p < 4; ++p){
      uint4v v = *(const uint4v*)(ap + (size_t)((p << 8) + t) * 4);
      #pragma unroll
      for (int j = 0; j < 4; ++j){
        const int E = ((p << 8) + t) * 4 + j;
        st[(E >> 4) * 17 + (E & 15)] = v[j];
      }
    }
    __syncthreads();
    #pragma unroll
    for (int j = 0; j < 16; ++j) if ((st[t * 17 + j] << 1) != 0u) word |= (2u << (2 * j));
  }
  pk[(size_t)blockIdx.x * 256 + t] = word;
}

// One-shot Q/K/V fp32 -> pre-swizzled bf16 hi/lo tile planes.
// Layout: cvt[(arr*1024 + panel*16 + tile) * 16384] = [hi 8192 B | lo 8192 B],
// hi/lo planes in swizzled order so a LINEAR copy to LDS reproduces the
// swizzled tile. V is stored transposed (VT[d][m]) via padded-LDS transpose.
__global__ __launch_bounds__(256) void precvt_kernel(const float* __restrict__ Q,
                                                     const float* __restrict__ K,
                                                     const float* __restrict__ V,
                                                     char* __restrict__ cvt){
  __shared__ float lt[64][65];
  const int job = blockIdx.x;                 // 0..3071
  const int arr = job >> 10;                  // 0:Q 1:K 2:V
  const int pt  = job & 1023;                 // panel*16 + tile
  const float* srcBase = (arr == 0) ? Q : ((arr == 1) ? K : V);
  const float* src = srcBase + ((size_t)(pt >> 4) * NDIM + (size_t)(pt & 15) * 64) * DDIM;
  char* dst = cvt + ((size_t)job << 14);
  short* dh = (short*)dst;
  short* dl = (short*)(dst + 8192);
  const int t = threadIdx.x;

  if (arr < 2){
    // output-linear: thread writes 2 contiguous 16B hi chunks (and lo), reads
    // the inverse-swizzled source chunks (full rows covered -> coalesced).
    const int r = t >> 2;
    #pragma unroll
    for (int k = 0; k < 2; ++k){
      const int cc = ((t & 3) << 1) + k;
      const int cs = cc ^ (r & 7);
      float4v v0 = *(const float4v*)(src + r * 64 + cs * 8);
      float4v v1 = *(const float4v*)(src + r * 64 + cs * 8 + 4);
      short8 hv, lv;
      #pragma unroll
      for (int j = 0; j < 4; ++j){
        short hb = f2bf(v0[j]); hv[j] = hb;     lv[j] = f2bf(v0[j] - bf2f(hb));
        short h2 = f2bf(v1[j]); hv[j + 4] = h2; lv[j + 4] = f2bf(v1[j] - bf2f(h2));
      }
      *(short8*)(dh + r * 64 + cc * 8) = hv;
      *(short8*)(dl + r * 64 + cc * 8) = lv;
    }
  } else {
    // V: coalesced fp32 read -> padded LDS -> transposed swizzled bf16 write.
    const int m = t >> 2;
    #pragma unroll
    for (int k = 0; k < 4; ++k){
      const int c = ((t & 3) << 2) + (k << 4);
      float4v v = *(const float4v*)(src + m * 64 + c);
      lt[m][c] = v[0]; lt[m][c + 1] = v[1]; lt[m][c + 2] = v[2]; lt[m][c + 3] = v[3];
    }
    __syncthreads();
    const int d = t >> 2;
    #pragma unroll
    for (int k = 0; k < 2; ++k){
      const int cc = ((t & 3) << 1) + k;
      const int ms = (cc ^ (d & 7)) << 3;
      short8 hv, lv;
      #pragma unroll
      for (int j = 0; j < 8; ++j){
        float x = lt[ms + j][d];
        short hb = f2bf(x); hv[j] = hb; lv[j] = f2bf(x - bf2f(hb));
      }
      *(short8*)(dh + d * 64 + cc * 8) = hv;
      *(short8*)(dl + d * 64 + cc * 8) = lv;
    }
  }
}

template<int MODE>
__global__ __launch_bounds__(256) void msrsa_main(
    const float* __restrict__ Q, const float* __restrict__ K, const float* __restrict__ V,
    const void* __restrict__ maskp, const float* __restrict__ adjp,
    const float* __restrict__ wAp,
    float* __restrict__ outp, float* __restrict__ attnp,
    const unsigned int* __restrict__ pk, const int* __restrict__ flagp,
    const char* __restrict__ cvt)
{
  // XCD-aware bijective swizzle: 16 blocks sharing one (b,h) K/V panel -> one XCD.
  const int p   = blockIdx.x;
  const int blk = (p & 7) * 128 + (p >> 3);
  const int b  = blk >> 7;
  const int h  = (blk >> 4) & 7;
  const int rb = blk & 15;
  const int n0 = rb << 6;
  const int tid  = threadIdx.x;
  const int wid  = tid >> 6;
  const int lane = tid & 63;
  const int g    = lane >> 4;
  const int q    = lane & 15;

  const size_t bh = (size_t)(b * HDIM + h);
  const float* Qb = Q + bh * (NDIM * DDIM) + (size_t)n0 * DDIM;
  const float* Kb = K + bh * (NDIM * DDIM);
  const float* Vb = V + bh * (NDIM * DDIM);
  const char* Qc = cvt + (((size_t)0 + bh * 16 + rb) << 14);
  const char* Kc = cvt + (((size_t)1024 + bh * 16) << 14);
  const char* Vc = cvt + (((size_t)2048 + bh * 16) << 14);
  const float c0 = 0.125f;
  const float cA = (1.0f + wAp[h]) * 0.125f;
  int flag = 0;
  if (MODE == 0) flag = flagp[0];
  const size_t bNN = (size_t)b * ((size_t)NDIM * NDIM);

  __shared__ __align__(16) char A0[16384];   // Q staging, then P tiles
  __shared__ __align__(16) char A1[16384];   // K tiles
  __shared__ __align__(16) char A2[16384];   // V^T tiles
  short* A0h = (short*)A0;  short* A0l = (short*)(A0 + 8192);
  short* A1h = (short*)A1;  short* A1l = (short*)(A1 + 8192);
  short* A2h = (short*)A2;  short* A2l = (short*)(A2 + 8192);

  if (MODE == 2) copyTile(Qc, A0, wid, lane);
  else           stageHL(Qb, A0h, A0l, tid);
  __syncthreads();
  const int arow = (wid << 4) + q;
  short8 qh[2], ql[2];
  qh[0] = ldsFrag(A0h, arow, g);  qh[1] = ldsFrag(A0h, arow, g + 4);
  ql[0] = ldsFrag(A0l, arow, g);  ql[1] = ldsFrag(A0l, arow, g + 4);

  int nloc[4];
  #pragma unroll
  for (int i = 0; i < 4; ++i) nloc[i] = (wid << 4) + (g << 2) + i;

  // ---------------- pass A: row sums ----------------
  float psum[4] = {0.f, 0.f, 0.f, 0.f};
  for (int ms = 0; ms < 16; ++ms){
    const int m0 = ms << 6;
    __syncthreads();
    if (MODE == 2) copyTile(Kc + ((size_t)ms << 14), A1, wid, lane);
    else           stageHL(Kb + m0 * DDIM, A1h, A1l, tid);
    __syncthreads();
    #pragma unroll
    for (int mt = 0; mt < 4; ++mt){
      float4v acc = {0.f, 0.f, 0.f, 0.f};
      const int brow = (mt << 4) + q;
      #pragma unroll
      for (int ks = 0; ks < 2; ++ks){
        short8 kh = ldsFrag(A1h, brow, g + (ks << 2));
        short8 kl = ldsFrag(A1l, brow, g + (ks << 2));
        acc = mfma16(qh[ks], kh, acc);
        acc = mfma16(qh[ks], kl, acc);
        acc = mfma16(ql[ks], kh, acc);
      }
      #pragma unroll
      for (int i = 0; i < 4; ++i){
        const int n = n0 + nloc[i];
        float coef;
        if (MODE >= 1){
          unsigned int wv = pk[((unsigned)b << 16) + ((unsigned)n << 6) + (unsigned)((m0 >> 4) + mt)];
          unsigned int bits = (wv >> (q << 1)) & 3u;
          coef = (bits & 1u) ? ((bits & 2u) ? cA : c0) : 0.0f;
        } else {
          const size_t ei = bNN + (size_t)n * NDIM + (size_t)(m0 + (mt << 4) + q);
          bool mk;
          if (flag == 0)      mk = ((const int*)maskp)[ei] != 0;
          else if (flag == 1) mk = ((const unsigned char*)maskp)[ei] != 0;
          else                mk = ((const float*)maskp)[ei] != 0.f;
          float av = adjp[ei];
          coef = mk ? ((av != 0.f) ? cA : c0) : 0.f;
        }
        psum[i] += __expf(acc[i] * coef);
      }
    }
  }
  float inv[4];
  #pragma unroll
  for (int i = 0; i < 4; ++i){
    float s = psum[i];
    s += __shfl_xor(s, 1, 16);
    s += __shfl_xor(s, 2, 16);
    s += __shfl_xor(s, 4, 16);
    s += __shfl_xor(s, 8, 16);
    inv[i] = 1.0f / s;
  }

  // ---------------- pass B: attn store + PV ----------------
  float4v oacc[4];
  #pragma unroll
  for (int dt = 0; dt < 4; ++dt) oacc[dt] = (float4v){0.f, 0.f, 0.f, 0.f};

  float* aRow[4];
  #pragma unroll
  for (int i = 0; i < 4; ++i)
    aRow[i] = attnp + (bh * NDIM + (size_t)(n0 + nloc[i])) * (size_t)NDIM;

  for (int ms = 0; ms < 16; ++ms){
    const int m0 = ms << 6;
    __syncthreads();
    if (MODE == 2){
      copyTile(Kc + ((size_t)ms << 14), A1, wid, lane);
      copyTile(Vc + ((size_t)ms << 14), A2, wid, lane);
    } else {
      stageHL(Kb + m0 * DDIM, A1h, A1l, tid);
      stageVT(Vb + m0 * DDIM, A2h, A2l, tid);
    }
    __syncthreads();
    #pragma unroll
    for (int mt = 0; mt < 4; ++mt){
      float4v acc = {0.f, 0.f, 0.f, 0.f};
      const int brow = (mt << 4) + q;
      #pragma unroll
      for (int ks = 0; ks < 2; ++ks){
        short8 kh = ldsFrag(A1h, brow, g + (ks << 2));
        short8 kl = ldsFrag(A1l, brow, g + (ks << 2));
        acc = mfma16(qh[ks], kh, acc);
        acc = mfma16(qh[ks], kl, acc);
        acc = mfma16(ql[ks], kh, acc);
      }
      #pragma unroll
      for (int i = 0; i < 4; ++i){
        const int n = n0 + nloc[i];
        float coef;
        if (MODE >= 1){
          unsigned int wv = pk[((unsigned)b << 16) + ((unsigned)n << 6) + (unsigned)((m0 >> 4) + mt)];
          unsigned int bits = (wv >> (q << 1)) & 3u;
          coef = (bits & 1u) ? ((bits & 2u) ? cA : c0) : 0.0f;
        } else {
          const size_t ei = bNN + (size_t)n * NDIM + (size_t)(m0 + (mt << 4) + q);
          bool mk;
          if (flag == 0)      mk = ((const int*)maskp)[ei] != 0;
          else if (flag == 1) mk = ((const unsigned char*)maskp)[ei] != 0;
          else                mk = ((const float*)maskp)[ei] != 0.f;
          float av = adjp[ei];
          coef = mk ? ((av != 0.f) ? cA : c0) : 0.f;
        }
        float p2 = __expf(acc[i] * coef);
        float at = p2 * inv[i];
        aRow[i][m0 + (mt << 4) + q] = at;
        short ph = f2bf(at);
        const int pi = swz(nloc[i], (mt << 4) + q);
        A0h[pi] = ph;
        A0l[pi] = f2bf(at - bf2f(ph));
      }
    }
    __syncthreads();
    #pragma unroll
    for (int ks = 0; ks < 2; ++ks){
      short8 pah = ldsFrag(A0h, arow, g + (ks << 2));
      short8 pal = ldsFrag(A0l, arow, g + (ks << 2));
      #pragma unroll
      for (int dt = 0; dt < 4; ++dt){
        short8 vh = ldsFrag(A2h, (dt << 4) + q, g + (ks << 2));
        short8 vl = ldsFrag(A2l, (dt << 4) + q, g + (ks << 2));
        oacc[dt] = mfma16(pah, vh, oacc[dt]);
        oacc[dt] = mfma16(pah, vl, oacc[dt]);
        oacc[dt] = mfma16(pal, vh, oacc[dt]);
      }
    }
  }

  #pragma unroll
  for (int dt = 0; dt < 4; ++dt){
    #pragma unroll
    for (int i = 0; i < 4; ++i){
      outp[(bh * NDIM + (size_t)(n0 + nloc[i])) * DDIM + (dt << 4) + q] = oacc[dt][i];
    }
  }
}

extern "C" void kernel_launch(void* const* d_in, const int* in_sizes, int n_in,
                              void* d_out, int out_size, void* d_ws, size_t ws_size,
                              hipStream_t stream){
  const float* Q    = (const float*)d_in[0];
  const float* K    = (const float*)d_in[1];
  const float* V    = (const float*)d_in[2];
  const void*  mskp = d_in[3];
  const float* adjp = (const float*)d_in[4];
  // d_in[5] (row_subtracted_distance_matrix) unused by reference
  const float* wAp  = (const float*)d_in[6];

  float* outp  = (float*)d_out;
  float* attnp = outp + (size_t)BDIM * HDIM * NDIM * DDIM;

  int* flagp = (int*)d_ws;
  unsigned int* pkbuf = (unsigned int*)((char*)d_ws + 256);
  char* cvtbuf = (char*)d_ws + 256 + (size_t)2 * 1024 * 1024;
  const size_t needPk  = 256 + (size_t)2 * 1024 * 1024;
  const size_t needCvt = needPk + (size_t)48 * 1024 * 1024;

  hipLaunchKernelGGL(detect_kernel, dim3(1), dim3(256), 0, stream,
                     (const unsigned int*)mskp, flagp);
  if (ws_size >= needCvt){
    hipLaunchKernelGGL(pack_kernel, dim3(2048), dim3(256), 0, stream,
                       mskp, adjp, flagp, pkbuf);
    hipLaunchKernelGGL(precvt_kernel, dim3(3072), dim3(256), 0, stream,
                       Q, K, V, cvtbuf);
    hipLaunchKernelGGL(msrsa_main<2>, dim3(1024), dim3(256), 0, stream,
                       Q, K, V, mskp, adjp, wAp, outp, attnp, pkbuf, flagp, cvtbuf);
  } else if (ws_size >= needPk){
    hipLaunchKernelGGL(pack_kernel, dim3(2048), dim3(256), 0, stream,
                       mskp, adjp, flagp, pkbuf);
    hipLaunchKernelGGL(msrsa_main<1>, dim3(1024), dim3(256), 0, stream,
                       Q, K, V, mskp, adjp, wAp, outp, attnp, pkbuf, flagp, cvtbuf);
  } else {
    hipLaunchKernelGGL(msrsa_main<0>, dim3(1024), dim3(256), 0, stream,
                       Q, K, V, mskp, adjp, wAp, outp, attnp, pkbuf, flagp, cvtbuf);
  }
}

// Round 6
// 487.376 us; speedup vs baseline: 1.1642x; 1.0423x over previous
//
#include <hip/hip_runtime.h>

// MSRSA fused attention, MI355X gfx950.
// out[B,H,N,D] fp32  ++  attn[B,H,N,N] fp32   (d_out = out | attn, flat)
// B=8 H=8 N=1024 D=64.
//
// R5 -> R6: R5's raw s_barrier + counted-vmcnt schedule RACED (scattered attn
// corruption). Revert to __syncthreads-only (full drain = provably safe),
// keep the pipelining via ISSUE-EARLY prefetch:
//  pass A: prefetch K(ms+1) into ping-pong buffer BEFORE compute; 1 sync/iter
//          (drain overlapped by whole compute phase).
//  pass B: QK -> sync -> issue K(ms+1) -> exp/P/attn -> sync (drains K,
//          overlapped by exp; also orders P->PV like R4) -> PV -> sync ->
//          issue V(ms+1) (drained at NEXT iter's first sync, overlapped by QK).
// pk mask loads: 16 scalar -> 4 dwordx4 per lane per iter.
// Output path bit-identical to R4 (passed, absmax 0.0078125).

typedef __attribute__((ext_vector_type(8))) short short8;
typedef __attribute__((ext_vector_type(4))) short short4v;
typedef __attribute__((ext_vector_type(4))) float float4v;
typedef __attribute__((ext_vector_type(4))) unsigned int uint4v;

#define BDIM 8
#define HDIM 8
#define NDIM 1024
#define DDIM 64

__device__ __forceinline__ short f2bf(float x){
  unsigned int u = __float_as_uint(x);
  unsigned int r = (u + 0x7fffu + ((u >> 16) & 1u)) >> 16;
  return (short)r;
}
__device__ __forceinline__ float bf2f(short s){
  return __uint_as_float(((unsigned int)(unsigned short)s) << 16);
}
__device__ __forceinline__ int swz(int r, int c){
  return r * 64 + ((((c >> 3) ^ (r & 7))) << 3) + (c & 7);
}
__device__ __forceinline__ short8 ldsFrag(const short* base, int row, int ch){
  return *(const short8*)(base + row * 64 + ((ch ^ (row & 7)) << 3));
}
__device__ __forceinline__ float4v mfma16(short8 a, short8 b, float4v c){
  return __builtin_amdgcn_mfma_f32_16x16x32_bf16(a, b, c, 0, 0, 0);
}

// async global->LDS 16B/lane. LDS dest wave-uniform; HW adds lane*16.
__device__ __forceinline__ void gload16(const void* g, void* l){
  __builtin_amdgcn_global_load_lds(
      (const __attribute__((address_space(1))) unsigned int*)g,
      (__attribute__((address_space(3))) unsigned int*)l, 16, 0, 0);
}
// copy one 16 KiB pre-swizzled tile into LDS; 4 vmem ops per wave.
__device__ __forceinline__ void copyTile(const char* g, char* l, int wid, int lane){
  #pragma unroll
  for (int c = 0; c < 4; ++c){
    gload16(g + (c << 12) + (wid << 10) + (lane << 4),
            l + (c << 12) + (wid << 10));
  }
}

// ---- legacy inline staging (MODE<2 fallback), identical numerics ----
__device__ __forceinline__ void stageHL(const float* __restrict__ gsrc,
                                        short* ldsH, short* ldsL, int tid){
  const int r  = tid >> 2;
  const int cb = (tid & 3) << 2;
  #pragma unroll
  for (int k = 0; k < 4; ++k){
    const int c = cb + (k << 4);
    float4v v = *(const float4v*)(gsrc + r * 64 + c);
    short4v hv, lv;
    #pragma unroll
    for (int j = 0; j < 4; ++j){
      float x = v[j];
      short hb = f2bf(x);
      hv[j] = hb;
      lv[j] = f2bf(x - bf2f(hb));
    }
    const int idx = swz(r, c);
    *(short4v*)(ldsH + idx) = hv;
    *(short4v*)(ldsL + idx) = lv;
  }
}
__device__ __forceinline__ void stageVT(const float* __restrict__ gsrc,
                                        short* ldsH, short* ldsL, int tid){
  const int m  = tid >> 2;
  const int db = (tid & 3) << 2;
  #pragma unroll
  for (int k = 0; k < 4; ++k){
    const int d0 = db + (k << 4);
    float4v v = *(const float4v*)(gsrc + m * 64 + d0);
    #pragma unroll
    for (int j = 0; j < 4; ++j){
      float x = v[j];
      short hb = f2bf(x);
      const int idx = swz(d0 + j, m);
      ldsH[idx] = hb;
      ldsL[idx] = f2bf(x - bf2f(hb));
    }
  }
}

__global__ void detect_kernel(const unsigned int* __restrict__ m, int* __restrict__ flag){
  __shared__ unsigned int fl;
  if (threadIdx.x == 0) fl = 0u;
  __syncthreads();
  unsigned int loc = 0u;
  #pragma unroll
  for (int j = 0; j < 4; ++j){
    unsigned int w = m[threadIdx.x * 4 + j];
    if (w == 0x3f800000u) loc |= 2u;
    else if (w > 1u)      loc |= 1u;
  }
  atomicOr(&fl, loc);
  __syncthreads();
  if (threadIdx.x == 0){
    int code = 0;
    if (fl & 2u) code = 2;
    else if (fl & 1u) code = 1;
    flag[0] = code;
  }
}

__global__ __launch_bounds__(256) void pack_kernel(const void* __restrict__ maskp,
                                                   const float* __restrict__ adjp,
                                                   const int* __restrict__ flagp,
                                                   unsigned int* __restrict__ pk){
  __shared__ unsigned int st[256 * 17];
  const int t = threadIdx.x;
  const size_t ebase = (size_t)blockIdx.x * 4096;
  const int fl = flagp[0];
  unsigned int word = 0u;

  if (fl == 1){
    uint4v mv = *(const uint4v*)((const unsigned char*)maskp + ebase + (size_t)t * 16);
    #pragma unroll
    for (int j = 0; j < 16; ++j){
      unsigned int byte = (mv[j >> 2] >> ((j & 3) * 8)) & 0xffu;
      if (byte) word |= (1u << (2 * j));
    }
  } else {
    const unsigned int* mp = (const unsigned int*)maskp + ebase;
    #pragma unroll
    for (int p = 0; p < 4; ++p){
      uint4v v = *(const uint4v*)(mp + (size_t)((p << 8) + t) * 4);
      #pragma unroll
      for (int j = 0; j < 4; ++j){
        const int E = ((p << 8) + t) * 4 + j;
        st[(E >> 4) * 17 + (E & 15)] = v[j];
      }
    }
    __syncthreads();
    #pragma unroll
    for (int j = 0; j < 16; ++j) if (st[t * 17 + j] != 0u) word |= (1u << (2 * j));
    __syncthreads();
  }

  {
    const unsigned int* ap = (const unsigned int*)adjp + ebase;
    #pragma unroll
    for (int p = 0; p < 4; ++p){
      uint4v v = *(const uint4v*)(ap + (size_t)((p << 8) + t) * 4);
      #pragma unroll
      for (int j = 0; j < 4; ++j){
        const int E = ((p << 8) + t) * 4 + j;
        st[(E >> 4) * 17 + (E & 15)] = v[j];
      }
    }
    __syncthreads();
    #pragma unroll
    for (int j = 0; j < 16; ++j) if ((st[t * 17 + j] << 1) != 0u) word |= (2u << (2 * j));
  }
  pk[(size_t)blockIdx.x * 256 + t] = word;
}

// One-shot Q/K/V fp32 -> pre-swizzled bf16 hi/lo tile planes (48 MiB in d_ws).
__global__ __launch_bounds__(256) void precvt_kernel(const float* __restrict__ Q,
                                                     const float* __restrict__ K,
                                                     const float* __restrict__ V,
                                                     char* __restrict__ cvt){
  __shared__ float lt[64][65];
  const int job = blockIdx.x;
  const int arr = job >> 10;
  const int pt  = job & 1023;
  const float* srcBase = (arr == 0) ? Q : ((arr == 1) ? K : V);
  const float* src = srcBase + ((size_t)(pt >> 4) * NDIM + (size_t)(pt & 15) * 64) * DDIM;
  char* dst = cvt + ((size_t)job << 14);
  short* dh = (short*)dst;
  short* dl = (short*)(dst + 8192);
  const int t = threadIdx.x;

  if (arr < 2){
    const int r = t >> 2;
    #pragma unroll
    for (int k = 0; k < 2; ++k){
      const int cc = ((t & 3) << 1) + k;
      const int cs = cc ^ (r & 7);
      float4v v0 = *(const float4v*)(src + r * 64 + cs * 8);
      float4v v1 = *(const float4v*)(src + r * 64 + cs * 8 + 4);
      short8 hv, lv;
      #pragma unroll
      for (int j = 0; j < 4; ++j){
        short hb = f2bf(v0[j]); hv[j] = hb;     lv[j] = f2bf(v0[j] - bf2f(hb));
        short h2 = f2bf(v1[j]); hv[j + 4] = h2; lv[j + 4] = f2bf(v1[j] - bf2f(h2));
      }
      *(short8*)(dh + r * 64 + cc * 8) = hv;
      *(short8*)(dl + r * 64 + cc * 8) = lv;
    }
  } else {
    const int m = t >> 2;
    #pragma unroll
    for (int k = 0; k < 4; ++k){
      const int c = ((t & 3) << 2) + (k << 4);
      float4v v = *(const float4v*)(src + m * 64 + c);
      lt[m][c] = v[0]; lt[m][c + 1] = v[1]; lt[m][c + 2] = v[2]; lt[m][c + 3] = v[3];
    }
    __syncthreads();
    const int d = t >> 2;
    #pragma unroll
    for (int k = 0; k < 2; ++k){
      const int cc = ((t & 3) << 1) + k;
      const int ms = (cc ^ (d & 7)) << 3;
      short8 hv, lv;
      #pragma unroll
      for (int j = 0; j < 8; ++j){
        float x = lt[ms + j][d];
        short hb = f2bf(x); hv[j] = hb; lv[j] = f2bf(x - bf2f(hb));
      }
      *(short8*)(dh + d * 64 + cc * 8) = hv;
      *(short8*)(dl + d * 64 + cc * 8) = lv;
    }
  }
}

// ---------------- MODE2 fast path: issue-early prefetch, syncthreads-only ----------------
__global__ __launch_bounds__(256) void msrsa_main2(
    const float* __restrict__ wAp,
    float* __restrict__ outp, float* __restrict__ attnp,
    const unsigned int* __restrict__ pk, const char* __restrict__ cvt)
{
  const int p   = blockIdx.x;
  const int blk = (p & 7) * 128 + (p >> 3);        // XCD-aware swizzle
  const int b  = blk >> 7;
  const int h  = (blk >> 4) & 7;
  const int rb = blk & 15;
  const int n0 = rb << 6;
  const int tid  = threadIdx.x;
  const int wid  = tid >> 6;
  const int lane = tid & 63;
  const int g    = lane >> 4;
  const int q    = lane & 15;

  const size_t bh = (size_t)(b * HDIM + h);
  const char* Qc = cvt + (((size_t)0 + bh * 16 + rb) << 14);
  const char* Kc = cvt + (((size_t)1024 + bh * 16) << 14);
  const char* Vc = cvt + (((size_t)2048 + bh * 16) << 14);
  const float c0 = 0.125f;
  const float cA = (1.0f + wAp[h]) * 0.125f;

  __shared__ __align__(16) char A0[16384];   // Q staging, then P tiles (wave-private rows)
  __shared__ __align__(16) char A1[16384];   // K ping-pong buf 0 / pass-B K
  __shared__ __align__(16) char A2[16384];   // pass A: K buf 1; pass B: V
  short* A0h = (short*)A0;  short* A0l = (short*)(A0 + 8192);

  // prologue: Q + K0
  copyTile(Qc, A0, wid, lane);
  copyTile(Kc, A1, wid, lane);
  __syncthreads();

  const int arow = (wid << 4) + q;
  short8 qh[2], ql[2];
  qh[0] = ldsFrag(A0h, arow, g);  qh[1] = ldsFrag(A0h, arow, g + 4);
  ql[0] = ldsFrag(A0l, arow, g);  ql[1] = ldsFrag(A0l, arow, g + 4);

  int nloc[4];
  #pragma unroll
  for (int i = 0; i < 4; ++i) nloc[i] = (wid << 4) + (g << 2) + i;

  // per-lane pk row bases (word index): pk[(b<<16) + (n<<6) + ms*4 + mt]
  const unsigned int* pkb[4];
  #pragma unroll
  for (int i = 0; i < 4; ++i)
    pkb[i] = pk + ((unsigned)b << 16) + ((unsigned)(n0 + nloc[i]) << 6);

  // ---------------- pass A: row sums (K ping-pong A1/A2, 1 sync/iter) ----------------
  float psum[4] = {0.f, 0.f, 0.f, 0.f};
  for (int ms = 0; ms < 16; ++ms){
    if (ms < 15) copyTile(Kc + ((size_t)(ms + 1) << 14),
                          ((ms + 1) & 1) ? A2 : A1, wid, lane);
    const short* Bh = (const short*)((ms & 1) ? A2 : A1);
    const short* Bl = Bh + 4096;
    uint4v pw[4];
    #pragma unroll
    for (int i = 0; i < 4; ++i) pw[i] = *(const uint4v*)(pkb[i] + (ms << 2));
    #pragma unroll
    for (int mt = 0; mt < 4; ++mt){
      float4v acc = {0.f, 0.f, 0.f, 0.f};
      const int brow = (mt << 4) + q;
      #pragma unroll
      for (int ks = 0; ks < 2; ++ks){
        short8 kh = ldsFrag(Bh, brow, g + (ks << 2));
        short8 kl = ldsFrag(Bl, brow, g + (ks << 2));
        acc = mfma16(qh[ks], kh, acc);
        acc = mfma16(qh[ks], kl, acc);
        acc = mfma16(ql[ks], kh, acc);
      }
      #pragma unroll
      for (int i = 0; i < 4; ++i){
        unsigned int bits = (pw[i][mt] >> (q << 1)) & 3u;
        float coef = (bits & 1u) ? ((bits & 2u) ? cA : c0) : 0.0f;
        psum[i] += __expf(acc[i] * coef);
      }
    }
    __syncthreads();   // joins readers of cur buf; drains prefetch (overlapped by compute)
  }
  float inv[4];
  #pragma unroll
  for (int i = 0; i < 4; ++i){
    float s = psum[i];
    s += __shfl_xor(s, 1, 16);
    s += __shfl_xor(s, 2, 16);
    s += __shfl_xor(s, 4, 16);
    s += __shfl_xor(s, 8, 16);
    inv[i] = 1.0f / s;
  }

  // ---------------- transition: stage K0 + V0 ----------------
  copyTile(Kc, A1, wid, lane);
  copyTile(Vc, A2, wid, lane);
  __syncthreads();

  // ---------------- pass B: attn store + PV (3 syncs/iter, drains overlapped) ----------------
  float4v oacc[4];
  #pragma unroll
  for (int dt = 0; dt < 4; ++dt) oacc[dt] = (float4v){0.f, 0.f, 0.f, 0.f};

  float* aRow[4];
  #pragma unroll
  for (int i = 0; i < 4; ++i)
    aRow[i] = attnp + (bh * NDIM + (size_t)(n0 + nloc[i])) * (size_t)NDIM;

  for (int ms = 0; ms < 16; ++ms){
    // QK^T from A1 = K(ms)
    float4v acc[4];
    #pragma unroll
    for (int mt = 0; mt < 4; ++mt){
      float4v a = {0.f, 0.f, 0.f, 0.f};
      const int brow = (mt << 4) + q;
      #pragma unroll
      for (int ks = 0; ks < 2; ++ks){
        short8 kh = ldsFrag((const short*)A1, brow, g + (ks << 2));
        short8 kl = ldsFrag((const short*)A1 + 4096, brow, g + (ks << 2));
        a = mfma16(qh[ks], kh, a);
        a = mfma16(qh[ks], kl, a);
        a = mfma16(ql[ks], kh, a);
      }
      acc[mt] = a;
    }
    __syncthreads();   // (a) all waves done reading A1; drains V(ms) prefetch (overlapped by QK)
    if (ms < 15) copyTile(Kc + ((size_t)(ms + 1) << 14), A1, wid, lane);

    // exp + attn store + P-write (wave-private rows of A0)
    uint4v pw[4];
    #pragma unroll
    for (int i = 0; i < 4; ++i) pw[i] = *(const uint4v*)(pkb[i] + (ms << 2));
    #pragma unroll
    for (int mt = 0; mt < 4; ++mt){
      #pragma unroll
      for (int i = 0; i < 4; ++i){
        unsigned int bits = (pw[i][mt] >> (q << 1)) & 3u;
        float coef = (bits & 1u) ? ((bits & 2u) ? cA : c0) : 0.0f;
        float p2 = __expf(acc[mt][i] * coef);
        float at = p2 * inv[i];
        aRow[i][(ms << 6) + (mt << 4) + q] = at;
        short ph = f2bf(at);
        const int pi = swz(nloc[i], (mt << 4) + q);
        A0h[pi] = ph;
        A0l[pi] = f2bf(at - bf2f(ph));
      }
    }
    __syncthreads();   // (p) P visible; drains K(ms+1) (overlapped by exp phase)

    // PV from A0 (P) + A2 (V(ms))
    #pragma unroll
    for (int ks = 0; ks < 2; ++ks){
      short8 pah = ldsFrag(A0h, arow, g + (ks << 2));
      short8 pal = ldsFrag(A0l, arow, g + (ks << 2));
      #pragma unroll
      for (int dt = 0; dt < 4; ++dt){
        short8 vh = ldsFrag((const short*)A2, (dt << 4) + q, g + (ks << 2));
        short8 vl = ldsFrag((const short*)A2 + 4096, (dt << 4) + q, g + (ks << 2));
        oacc[dt] = mfma16(pah, vh, oacc[dt]);
        oacc[dt] = mfma16(pah, vl, oacc[dt]);
        oacc[dt] = mfma16(pal, vh, oacc[dt]);
      }
    }
    __syncthreads();   // (b) all waves done reading A2 (V(ms))
    if (ms < 15) copyTile(Vc + ((size_t)(ms + 1) << 14), A2, wid, lane);
    // V(ms+1) drains at next iteration's sync (a), overlapped by QK(ms+1)
  }

  #pragma unroll
  for (int dt = 0; dt < 4; ++dt){
    #pragma unroll
    for (int i = 0; i < 4; ++i){
      outp[(bh * NDIM + (size_t)(n0 + nloc[i])) * DDIM + (dt << 4) + q] = oacc[dt][i];
    }
  }
}

// ---------------- legacy fallback (MODE 0/1), unchanged numerics ----------------
template<int MODE>
__global__ __launch_bounds__(256) void msrsa_main(
    const float* __restrict__ Q, const float* __restrict__ K, const float* __restrict__ V,
    const void* __restrict__ maskp, const float* __restrict__ adjp,
    const float* __restrict__ wAp,
    float* __restrict__ outp, float* __restrict__ attnp,
    const unsigned int* __restrict__ pk, const int* __restrict__ flagp)
{
  const int p   = blockIdx.x;
  const int blk = (p & 7) * 128 + (p >> 3);
  const int b  = blk >> 7;
  const int h  = (blk >> 4) & 7;
  const int rb = blk & 15;
  const int n0 = rb << 6;
  const int tid  = threadIdx.x;
  const int wid  = tid >> 6;
  const int lane = tid & 63;
  const int g    = lane >> 4;
  const int q    = lane & 15;

  const size_t bh = (size_t)(b * HDIM + h);
  const float* Qb = Q + bh * (NDIM * DDIM) + (size_t)n0 * DDIM;
  const float* Kb = K + bh * (NDIM * DDIM);
  const float* Vb = V + bh * (NDIM * DDIM);
  const float c0 = 0.125f;
  const float cA = (1.0f + wAp[h]) * 0.125f;
  int flag = 0;
  if (MODE == 0) flag = flagp[0];
  const size_t bNN = (size_t)b * ((size_t)NDIM * NDIM);

  __shared__ __align__(16) char A0[16384];
  __shared__ __align__(16) char A1[16384];
  __shared__ __align__(16) char A2[16384];
  short* A0h = (short*)A0;  short* A0l = (short*)(A0 + 8192);
  short* A1h = (short*)A1;  short* A1l = (short*)(A1 + 8192);
  short* A2h = (short*)A2;  short* A2l = (short*)(A2 + 8192);

  stageHL(Qb, A0h, A0l, tid);
  __syncthreads();
  const int arow = (wid << 4) + q;
  short8 qh[2], ql[2];
  qh[0] = ldsFrag(A0h, arow, g);  qh[1] = ldsFrag(A0h, arow, g + 4);
  ql[0] = ldsFrag(A0l, arow, g);  ql[1] = ldsFrag(A0l, arow, g + 4);

  int nloc[4];
  #pragma unroll
  for (int i = 0; i < 4; ++i) nloc[i] = (wid << 4) + (g << 2) + i;

  float psum[4] = {0.f, 0.f, 0.f, 0.f};
  for (int ms = 0; ms < 16; ++ms){
    const int m0 = ms << 6;
    __syncthreads();
    stageHL(Kb + m0 * DDIM, A1h, A1l, tid);
    __syncthreads();
    #pragma unroll
    for (int mt = 0; mt < 4; ++mt){
      float4v acc = {0.f, 0.f, 0.f, 0.f};
      const int brow = (mt << 4) + q;
      #pragma unroll
      for (int ks = 0; ks < 2; ++ks){
        short8 kh = ldsFrag(A1h, brow, g + (ks << 2));
        short8 kl = ldsFrag(A1l, brow, g + (ks << 2));
        acc = mfma16(qh[ks], kh, acc);
        acc = mfma16(qh[ks], kl, acc);
        acc = mfma16(ql[ks], kh, acc);
      }
      #pragma unroll
      for (int i = 0; i < 4; ++i){
        const int n = n0 + nloc[i];
        float coef;
        if (MODE >= 1){
          unsigned int wv = pk[((unsigned)b << 16) + ((unsigned)n << 6) + (unsigned)((m0 >> 4) + mt)];
          unsigned int bits = (wv >> (q << 1)) & 3u;
          coef = (bits & 1u) ? ((bits & 2u) ? cA : c0) : 0.0f;
        } else {
          const size_t ei = bNN + (size_t)n * NDIM + (size_t)(m0 + (mt << 4) + q);
          bool mk;
          if (flag == 0)      mk = ((const int*)maskp)[ei] != 0;
          else if (flag == 1) mk = ((const unsigned char*)maskp)[ei] != 0;
          else                mk = ((const float*)maskp)[ei] != 0.f;
          float av = adjp[ei];
          coef = mk ? ((av != 0.f) ? cA : c0) : 0.f;
        }
        psum[i] += __expf(acc[i] * coef);
      }
    }
  }
  float inv[4];
  #pragma unroll
  for (int i = 0; i < 4; ++i){
    float s = psum[i];
    s += __shfl_xor(s, 1, 16);
    s += __shfl_xor(s, 2, 16);
    s += __shfl_xor(s, 4, 16);
    s += __shfl_xor(s, 8, 16);
    inv[i] = 1.0f / s;
  }

  float4v oacc[4];
  #pragma unroll
  for (int dt = 0; dt < 4; ++dt) oacc[dt] = (float4v){0.f, 0.f, 0.f, 0.f};

  float* aRow[4];
  #pragma unroll
  for (int i = 0; i < 4; ++i)
    aRow[i] = attnp + (bh * NDIM + (size_t)(n0 + nloc[i])) * (size_t)NDIM;

  for (int ms = 0; ms < 16; ++ms){
    const int m0 = ms << 6;
    __syncthreads();
    stageHL(Kb + m0 * DDIM, A1h, A1l, tid);
    stageVT(Vb + m0 * DDIM, A2h, A2l, tid);
    __syncthreads();
    #pragma unroll
    for (int mt = 0; mt < 4; ++mt){
      float4v acc = {0.f, 0.f, 0.f, 0.f};
      const int brow = (mt << 4) + q;
      #pragma unroll
      for (int ks = 0; ks < 2; ++ks){
        short8 kh = ldsFrag(A1h, brow, g + (ks << 2));
        short8 kl = ldsFrag(A1l, brow, g + (ks << 2));
        acc = mfma16(qh[ks], kh, acc);
        acc = mfma16(qh[ks], kl, acc);
        acc = mfma16(ql[ks], kh, acc);
      }
      #pragma unroll
      for (int i = 0; i < 4; ++i){
        const int n = n0 + nloc[i];
        float coef;
        if (MODE >= 1){
          unsigned int wv = pk[((unsigned)b << 16) + ((unsigned)n << 6) + (unsigned)((m0 >> 4) + mt)];
          unsigned int bits = (wv >> (q << 1)) & 3u;
          coef = (bits & 1u) ? ((bits & 2u) ? cA : c0) : 0.0f;
        } else {
          const size_t ei = bNN + (size_t)n * NDIM + (size_t)(m0 + (mt << 4) + q);
          bool mk;
          if (flag == 0)      mk = ((const int*)maskp)[ei] != 0;
          else if (flag == 1) mk = ((const unsigned char*)maskp)[ei] != 0;
          else                mk = ((const float*)maskp)[ei] != 0.f;
          float av = adjp[ei];
          coef = mk ? ((av != 0.f) ? cA : c0) : 0.f;
        }
        float p2 = __expf(acc[i] * coef);
        float at = p2 * inv[i];
        aRow[i][m0 + (mt << 4) + q] = at;
        short ph = f2bf(at);
        const int pi = swz(nloc[i], (mt << 4) + q);
        A0h[pi] = ph;
        A0l[pi] = f2bf(at - bf2f(ph));
      }
    }
    __syncthreads();
    #pragma unroll
    for (int ks = 0; ks < 2; ++ks){
      short8 pah = ldsFrag(A0h, arow, g + (ks << 2));
      short8 pal = ldsFrag(A0l, arow, g + (ks << 2));
      #pragma unroll
      for (int dt = 0; dt < 4; ++dt){
        short8 vh = ldsFrag(A2h, (dt << 4) + q, g + (ks << 2));
        short8 vl = ldsFrag(A2l, (dt << 4) + q, g + (ks << 2));
        oacc[dt] = mfma16(pah, vh, oacc[dt]);
        oacc[dt] = mfma16(pah, vl, oacc[dt]);
        oacc[dt] = mfma16(pal, vh, oacc[dt]);
      }
    }
  }

  #pragma unroll
  for (int dt = 0; dt < 4; ++dt){
    #pragma unroll
    for (int i = 0; i < 4; ++i){
      outp[(bh * NDIM + (size_t)(n0 + nloc[i])) * DDIM + (dt << 4) + q] = oacc[dt][i];
    }
  }
}

extern "C" void kernel_launch(void* const* d_in, const int* in_sizes, int n_in,
                              void* d_out, int out_size, void* d_ws, size_t ws_size,
                              hipStream_t stream){
  const float* Q    = (const float*)d_in[0];
  const float* K    = (const float*)d_in[1];
  const float* V    = (const float*)d_in[2];
  const void*  mskp = d_in[3];
  const float* adjp = (const float*)d_in[4];
  const float* wAp  = (const float*)d_in[6];

  float* outp  = (float*)d_out;
  float* attnp = outp + (size_t)BDIM * HDIM * NDIM * DDIM;

  int* flagp = (int*)d_ws;
  unsigned int* pkbuf = (unsigned int*)((char*)d_ws + 256);
  char* cvtbuf = (char*)d_ws + 256 + (size_t)2 * 1024 * 1024;
  const size_t needPk  = 256 + (size_t)2 * 1024 * 1024;
  const size_t needCvt = needPk + (size_t)48 * 1024 * 1024;

  hipLaunchKernelGGL(detect_kernel, dim3(1), dim3(256), 0, stream,
                     (const unsigned int*)mskp, flagp);
  if (ws_size >= needCvt){
    hipLaunchKernelGGL(pack_kernel, dim3(2048), dim3(256), 0, stream,
                       mskp, adjp, flagp, pkbuf);
    hipLaunchKernelGGL(precvt_kernel, dim3(3072), dim3(256), 0, stream,
                       Q, K, V, cvtbuf);
    hipLaunchKernelGGL(msrsa_main2, dim3(1024), dim3(256), 0, stream,
                       wAp, outp, attnp, pkbuf, cvtbuf);
  } else if (ws_size >= needPk){
    hipLaunchKernelGGL(msrsa_main<1>, dim3(1024), dim3(256), 0, stream,
                       Q, K, V, mskp, adjp, wAp, outp, attnp, pkbuf, flagp);
  } else {
    hipLaunchKernelGGL(msrsa_main<0>, dim3(1024), dim3(256), 0, stream,
                       Q, K, V, mskp, adjp, wAp, outp, attnp, pkbuf, flagp);
  }
}